// Round 1
// baseline (446.937 us; speedup 1.0000x reference)
//
#include <hip/hip_runtime.h>
#include <hip/hip_bf16.h>

#define ALPHA 0.2f
#define NEG_INF -9.0e15f
constexpr int N = 2048;
constexpr int HID = 64;
constexpr int H = 4;
constexpr int QS = 4; // q-splits in agg kernel

// ---------------- encoder: x = relu(nf@W1+b1)@W2+b2 ----------------
__global__ void enc_kernel(const float* __restrict__ nf,
                           const float* __restrict__ W1, const float* __restrict__ b1,
                           const float* __restrict__ W2, const float* __restrict__ b2,
                           float* __restrict__ x0) {
  int n = blockIdx.x;
  int j = threadIdx.x; // 64
  __shared__ float row[10];
  __shared__ float x1[64];
  if (j < 10) row[j] = nf[n * 10 + j];
  __syncthreads();
  float acc = b1[j];
#pragma unroll
  for (int k = 0; k < 10; k++) acc += row[k] * W1[k * 64 + j];
  x1[j] = fmaxf(acc, 0.f);
  __syncthreads();
  float acc2 = b2[j];
#pragma unroll
  for (int k = 0; k < 64; k++) acc2 += x1[k] * W2[k * 64 + j];
  x0[n * 64 + j] = acc2;
}

// ---------------- per-head projection h = x@W, plus s1,s2 ----------------
__global__ void h_kernel(const float* __restrict__ x, const float* __restrict__ W,
                         const float* __restrict__ a, float* __restrict__ h,
                         float* __restrict__ s1, float* __restrict__ s2,
                         int in_f, int F_out) {
  int n = blockIdx.x, head = blockIdx.y;
  int o = threadIdx.x; // 64
  extern __shared__ float xr[];
  for (int k = o; k < in_f; k += 64) xr[k] = x[(size_t)n * in_f + k];
  __syncthreads();
  float acc = 0.f;
  if (o < F_out) {
    const float* Wh = W + (size_t)head * in_f * F_out;
    for (int k = 0; k < in_f; k++) acc += xr[k] * Wh[k * F_out + o];
    h[((size_t)head * N + n) * F_out + o] = acc;
  }
  float p1 = 0.f, p2 = 0.f;
  if (o < F_out) {
    p1 = acc * a[head * 2 * F_out + o];
    p2 = acc * a[head * 2 * F_out + F_out + o];
  }
  for (int s = 32; s; s >>= 1) { p1 += __shfl_xor(p1, s); p2 += __shfl_xor(p2, s); }
  if (o == 0) { s1[head * N + n] = p1; s2[head * N + n] = p2; }
}

// ---------------- per-row softmax stats (max, denom) ----------------
__global__ void stats_kernel(const float* __restrict__ s1, const float* __restrict__ s2,
                             const int* __restrict__ adj,
                             float* __restrict__ mout, float* __restrict__ dout) {
  int p = blockIdx.x, head = blockIdx.y;
  const float* s1h = s1 + head * N;
  float s2p = s2[head * N + p];
  const size_t arow = (size_t)p * N;
  float mloc = -3.4e38f;
  for (int q = threadIdx.x; q < N; q += 256) {
    float e = s1h[q] + s2p;
    e = e > 0.f ? e : ALPHA * e;
    float ev = adj[arow + q] ? e : NEG_INF;
    mloc = fmaxf(mloc, ev);
  }
  __shared__ float red[4];
  for (int s = 32; s; s >>= 1) mloc = fmaxf(mloc, __shfl_xor(mloc, s));
  int wid = threadIdx.x >> 6;
  if ((threadIdx.x & 63) == 0) red[wid] = mloc;
  __syncthreads();
  float m = fmaxf(fmaxf(red[0], red[1]), fmaxf(red[2], red[3]));
  __syncthreads();
  float sloc = 0.f;
  for (int q = threadIdx.x; q < N; q += 256) {
    float e = s1h[q] + s2p;
    e = e > 0.f ? e : ALPHA * e;
    float ev = adj[arow + q] ? e : NEG_INF;
    sloc += __expf(ev - m);
  }
  for (int s = 32; s; s >>= 1) sloc += __shfl_xor(sloc, s);
  if ((threadIdx.x & 63) == 0) red[wid] = sloc;
  __syncthreads();
  if (threadIdx.x == 0) {
    mout[head * N + p] = m;
    dout[head * N + p] = red[0] + red[1] + red[2] + red[3];
  }
}

// ---------------- tiled attention aggregation (F=64) ----------------
// grid (N/64, H, QS), block 256. hp must be zeroed. hp += w @ h (unnormalized)
__global__ void agg_kernel(const float* __restrict__ h, const float* __restrict__ s1,
                           const float* __restrict__ s2, const float* __restrict__ mrow,
                           const int* __restrict__ adj, float* __restrict__ hp) {
  const int p0 = blockIdx.x * 64, head = blockIdx.y;
  __shared__ float ht[64][64];
  __shared__ float wt[64][65];
  const int tf = threadIdx.x & 15, tp = threadIdx.x >> 4;
  float acc[4][4] = {};
  const float* s1h = s1 + head * N;
  const float* hh = h + (size_t)head * N * 64;
  const int qt0 = blockIdx.z * (N / 64 / QS);
  for (int qt = qt0; qt < qt0 + (N / 64 / QS); ++qt) {
    const int q0 = qt * 64;
    __syncthreads();
    // stage h tile (coalesced)
#pragma unroll
    for (int k = 0; k < 16; k++) {
      int idx = threadIdx.x + 256 * k;
      int q = idx >> 6, f = idx & 63;
      ht[q][f] = hh[(size_t)(q0 + q) * 64 + f];
    }
    // fill w tile: wt[p][q] = exp(masked_e - m[p])  (uniform p per wave, coalesced q)
#pragma unroll
    for (int k = 0; k < 16; k++) {
      int idx = threadIdx.x + 256 * k;
      int pw = idx >> 6, qw = idx & 63;
      float e = s1h[q0 + qw] + s2[head * N + p0 + pw];
      e = e > 0.f ? e : ALPHA * e;
      float ev = adj[(size_t)(p0 + pw) * N + q0 + qw] ? e : NEG_INF;
      wt[pw][qw] = __expf(ev - mrow[head * N + p0 + pw]);
    }
    __syncthreads();
#pragma unroll 16
    for (int q = 0; q < 64; q++) {
      float4 hv = *(const float4*)(&ht[q][tf * 4]);
      float w0 = wt[tp * 4 + 0][q];
      float w1 = wt[tp * 4 + 1][q];
      float w2 = wt[tp * 4 + 2][q];
      float w3 = wt[tp * 4 + 3][q];
      acc[0][0] += w0 * hv.x; acc[0][1] += w0 * hv.y; acc[0][2] += w0 * hv.z; acc[0][3] += w0 * hv.w;
      acc[1][0] += w1 * hv.x; acc[1][1] += w1 * hv.y; acc[1][2] += w1 * hv.z; acc[1][3] += w1 * hv.w;
      acc[2][0] += w2 * hv.x; acc[2][1] += w2 * hv.y; acc[2][2] += w2 * hv.z; acc[2][3] += w2 * hv.w;
      acc[3][0] += w3 * hv.x; acc[3][1] += w3 * hv.y; acc[3][2] += w3 * hv.z; acc[3][3] += w3 * hv.w;
    }
  }
#pragma unroll
  for (int i = 0; i < 4; i++)
#pragma unroll
    for (int j = 0; j < 4; j++)
      atomicAdd(&hp[((size_t)head * N + p0 + tp * 4 + i) * 64 + tf * 4 + j], acc[i][j]);
}

// ---------------- epilogue: normalize, ELU, concat layout ----------------
__global__ void concat_elu_kernel(const float* __restrict__ hp, const float* __restrict__ denom,
                                  float* __restrict__ xout) {
  int idx = blockIdx.x * 256 + threadIdx.x; // H*N*64
  int f = idx & 63;
  int n = (idx >> 6) & (N - 1);
  int head = idx >> 17;
  float v = hp[idx] / denom[head * N + n];
  v = v > 0.f ? v : (__expf(v) - 1.f);
  xout[(size_t)n * (H * 64) + head * 64 + f] = v;
}

// ---------------- layer-2 aggregation (F=3) ----------------
__global__ void agg2_kernel(const float* __restrict__ h2, const float* __restrict__ s1,
                            const float* __restrict__ s2, const float* __restrict__ mrow,
                            const float* __restrict__ drow, const int* __restrict__ adj,
                            float* __restrict__ hp2) {
  int p = blockIdx.x, head = blockIdx.y;
  const float* s1h = s1 + head * N;
  float s2p = s2[head * N + p];
  float m = mrow[head * N + p];
  float a0 = 0, a1 = 0, a2 = 0;
  for (int q = threadIdx.x; q < N; q += 256) {
    float e = s1h[q] + s2p;
    e = e > 0.f ? e : ALPHA * e;
    float ev = adj[(size_t)p * N + q] ? e : NEG_INF;
    float w = __expf(ev - m);
    const float* hq = h2 + ((size_t)head * N + q) * 3;
    a0 += w * hq[0]; a1 += w * hq[1]; a2 += w * hq[2];
  }
  for (int s = 32; s; s >>= 1) {
    a0 += __shfl_xor(a0, s); a1 += __shfl_xor(a1, s); a2 += __shfl_xor(a2, s);
  }
  __shared__ float red[4][3];
  int wid = threadIdx.x >> 6;
  if ((threadIdx.x & 63) == 0) { red[wid][0] = a0; red[wid][1] = a1; red[wid][2] = a2; }
  __syncthreads();
  if (threadIdx.x < 3) {
    float v = red[0][threadIdx.x] + red[1][threadIdx.x] + red[2][threadIdx.x] + red[3][threadIdx.x];
    hp2[((size_t)head * N + p) * 3 + threadIdx.x] = v / drow[head * N + p];
  }
}

// ---------------- emb = elu(mean over heads) ----------------
__global__ void emb_kernel(const float* __restrict__ hp2, float* __restrict__ emb) {
  int idx = blockIdx.x * 256 + threadIdx.x; // N*3
  if (idx >= N * 3) return;
  float v = 0.25f * (hp2[idx] + hp2[N * 3 + idx] + hp2[2 * N * 3 + idx] + hp2[3 * N * 3 + idx]);
  v = v > 0.f ? v : (__expf(v) - 1.f);
  emb[idx] = v;
}

// ---------------- all-pairs edge classifier ----------------
// grid (8 q-tiles, 256 p-tiles), block 256: thread=q, 8 p rows per block
__global__ void cls_kernel(const float* __restrict__ emb,
                           const float* __restrict__ W1, const float* __restrict__ b1,
                           const float* __restrict__ W2, const float* __restrict__ b2,
                           float* __restrict__ out) {
  int q = blockIdx.x * 256 + threadIdx.x;
  int p0 = blockIdx.y * 8;
  __shared__ float ep[8][3];
  __shared__ float w1s[96], b1s[32], w2s[32];
  __shared__ float b2s;
  int t = threadIdx.x;
  if (t < 96) w1s[t] = W1[t];
  else if (t < 128) b1s[t - 96] = b1[t - 96];
  else if (t < 160) w2s[t - 128] = W2[t - 128];
  else if (t == 160) b2s = b2[0];
  else if (t >= 192 && t < 216) ((float*)ep)[t - 192] = emb[p0 * 3 + t - 192];
  __syncthreads();
  float e0 = emb[q * 3 + 0], e1 = emb[q * 3 + 1], e2 = emb[q * 3 + 2];
  float d[8][3];
#pragma unroll
  for (int i = 0; i < 8; i++) {
    d[i][0] = fabsf(ep[i][0] - e0);
    d[i][1] = fabsf(ep[i][1] - e1);
    d[i][2] = fabsf(ep[i][2] - e2);
  }
  float acc[8] = {0, 0, 0, 0, 0, 0, 0, 0};
#pragma unroll
  for (int j = 0; j < 32; j++) {
    float c0 = w1s[j], c1 = w1s[32 + j], c2 = w1s[64 + j], bb = b1s[j], w2 = w2s[j];
#pragma unroll
    for (int i = 0; i < 8; i++) {
      float hv = fmaxf(bb + d[i][0] * c0 + d[i][1] * c1 + d[i][2] * c2, 0.f);
      acc[i] += hv * w2;
    }
  }
#pragma unroll
  for (int i = 0; i < 8; i++) {
    float x = acc[i] + b2s;
    out[(size_t)(p0 + i) * N + q] = 1.f / (1.f + __expf(-x));
  }
}

extern "C" void kernel_launch(void* const* d_in, const int* in_sizes, int n_in,
                              void* d_out, int out_size, void* d_ws, size_t ws_size,
                              hipStream_t stream) {
  const float* nf    = (const float*)d_in[0];
  const int*   adj   = (const int*)d_in[1];
  const float* encW1 = (const float*)d_in[2];
  const float* encb1 = (const float*)d_in[3];
  const float* encW2 = (const float*)d_in[4];
  const float* encb2 = (const float*)d_in[5];
  const float* gatW0 = (const float*)d_in[6];
  const float* gata0 = (const float*)d_in[7];
  const float* gatW1 = (const float*)d_in[8];
  const float* gata1 = (const float*)d_in[9];
  const float* gatW2 = (const float*)d_in[10];
  const float* gata2 = (const float*)d_in[11];
  const float* clsW1 = (const float*)d_in[12];
  const float* clsb1 = (const float*)d_in[13];
  const float* clsW2 = (const float*)d_in[14];
  const float* clsb2 = (const float*)d_in[15];

  float* ws = (float*)d_ws;
  float* x0  = ws;                    // 2048*64
  float* h   = x0 + 131072;           // H*N*64
  float* s1  = h + 524288;            // H*N
  float* s2  = s1 + 8192;
  float* m   = s2 + 8192;
  float* dn  = m + 8192;
  float* xA  = dn + 8192;             // 2048*256
  float* xB  = xA + 524288;           // 2048*256
  float* hp  = xB + 524288;           // H*N*64 accumulator
  float* h2  = hp + 524288;           // H*N*3
  float* hp2 = h2 + 24576;            // H*N*3

  float* emb = (float*)d_out;         // 2048*3
  float* eprob = emb + N * 3;         // 2048*2048

  // encoder
  enc_kernel<<<dim3(N), dim3(64), 0, stream>>>(nf, encW1, encb1, encW2, encb2, x0);

  // ---- GAT layer 0 (in_f=64) ----
  h_kernel<<<dim3(N, H), dim3(64), 64 * sizeof(float), stream>>>(x0, gatW0, gata0, h, s1, s2, 64, 64);
  stats_kernel<<<dim3(N, H), dim3(256), 0, stream>>>(s1, s2, adj, m, dn);
  hipMemsetAsync(hp, 0, (size_t)H * N * 64 * sizeof(float), stream);
  agg_kernel<<<dim3(N / 64, H, QS), dim3(256), 0, stream>>>(h, s1, s2, m, adj, hp);
  concat_elu_kernel<<<dim3(H * N * 64 / 256), dim3(256), 0, stream>>>(hp, dn, xA);

  // ---- GAT layer 1 (in_f=256) ----
  h_kernel<<<dim3(N, H), dim3(64), 256 * sizeof(float), stream>>>(xA, gatW1, gata1, h, s1, s2, 256, 64);
  stats_kernel<<<dim3(N, H), dim3(256), 0, stream>>>(s1, s2, adj, m, dn);
  hipMemsetAsync(hp, 0, (size_t)H * N * 64 * sizeof(float), stream);
  agg_kernel<<<dim3(N / 64, H, QS), dim3(256), 0, stream>>>(h, s1, s2, m, adj, hp);
  concat_elu_kernel<<<dim3(H * N * 64 / 256), dim3(256), 0, stream>>>(hp, dn, xB);

  // ---- GAT layer 2 (in_f=256, F_out=3, mean over heads) ----
  h_kernel<<<dim3(N, H), dim3(64), 256 * sizeof(float), stream>>>(xB, gatW2, gata2, h2, s1, s2, 256, 3);
  stats_kernel<<<dim3(N, H), dim3(256), 0, stream>>>(s1, s2, adj, m, dn);
  agg2_kernel<<<dim3(N, H), dim3(256), 0, stream>>>(h2, s1, s2, m, dn, adj, hp2);
  emb_kernel<<<dim3((N * 3 + 255) / 256), dim3(256), 0, stream>>>(hp2, emb);

  // ---- classifier ----
  cls_kernel<<<dim3(8, N / 8), dim3(256), 0, stream>>>(emb, clsW1, clsb1, clsW2, clsb2, eprob);
}

// Round 2
// 256.715 us; speedup vs baseline: 1.7410x; 1.7410x over previous
//
#include <hip/hip_runtime.h>
#include <hip/hip_bf16.h>

#define ALPHA 0.2f
constexpr int N = 2048;
constexpr int H = 4;
constexpr int QS = 8;      // q-splits in agg kernel
constexpr int NW = N / 64; // 32 mask words per row

// ---------------- pack adjacency into bitmask: mask[p*32+w] covers q=w*64..+63 ----------------
__global__ void pack_adj_kernel(const int* __restrict__ adj, unsigned long long* __restrict__ mask) {
  int word = blockIdx.x * 4 + (threadIdx.x >> 6);
  int lane = threadIdx.x & 63;
  unsigned long long b = __ballot(adj[(size_t)word * 64 + lane] != 0);
  if (lane == 0) mask[word] = b;
}

// ---------------- encoder: x = relu(nf@W1+b1)@W2+b2 ----------------
__global__ void enc_kernel(const float* __restrict__ nf,
                           const float* __restrict__ W1, const float* __restrict__ b1,
                           const float* __restrict__ W2, const float* __restrict__ b2,
                           float* __restrict__ x0) {
  int n = blockIdx.x;
  int j = threadIdx.x; // 64
  __shared__ float row[10];
  __shared__ float x1[64];
  if (j < 10) row[j] = nf[n * 10 + j];
  __syncthreads();
  float acc = b1[j];
#pragma unroll
  for (int k = 0; k < 10; k++) acc += row[k] * W1[k * 64 + j];
  x1[j] = fmaxf(acc, 0.f);
  __syncthreads();
  float acc2 = b2[j];
#pragma unroll
  for (int k = 0; k < 64; k++) acc2 += x1[k] * W2[k * 64 + j];
  x0[n * 64 + j] = acc2;
}

// ---------------- projection h = x@W for all 4 heads, 4 nodes per block; also s1,s2 ----------------
__global__ void h_all_kernel(const float* __restrict__ x, const float* __restrict__ W,
                             const float* __restrict__ a, float* __restrict__ h,
                             float* __restrict__ s1, float* __restrict__ s2, int in_f) {
  const int n0 = blockIdx.x * 4;
  const int head = threadIdx.x >> 6, o = threadIdx.x & 63;
  extern __shared__ float xr[]; // 4 * in_f
  for (int k = threadIdx.x; k < 4 * in_f; k += 256) xr[k] = x[(size_t)n0 * in_f + k];
  __syncthreads();
  const float* __restrict__ Wh = W + (size_t)head * in_f * 64;
  float acc[4] = {0.f, 0.f, 0.f, 0.f};
#pragma unroll 4
  for (int k = 0; k < in_f; k++) {
    float wv = Wh[k * 64 + o];
    acc[0] = fmaf(xr[k], wv, acc[0]);
    acc[1] = fmaf(xr[in_f + k], wv, acc[1]);
    acc[2] = fmaf(xr[2 * in_f + k], wv, acc[2]);
    acc[3] = fmaf(xr[3 * in_f + k], wv, acc[3]);
  }
  const float aa1 = a[head * 128 + o];
  const float aa2 = a[head * 128 + 64 + o];
#pragma unroll
  for (int j = 0; j < 4; j++) {
    h[((size_t)head * N + n0 + j) * 64 + o] = acc[j];
    float p1 = acc[j] * aa1, p2 = acc[j] * aa2;
    for (int s = 32; s; s >>= 1) { p1 += __shfl_xor(p1, s); p2 += __shfl_xor(p2, s); }
    if (o == 0) { s1[head * N + n0 + j] = p1; s2[head * N + n0 + j] = p2; }
  }
}

// ---------------- layer-2 projection (F_out=3) ----------------
__global__ void h3_kernel(const float* __restrict__ x, const float* __restrict__ W,
                          const float* __restrict__ a, float* __restrict__ h2,
                          float* __restrict__ s1, float* __restrict__ s2) {
  const int n = blockIdx.x;
  const int head = threadIdx.x >> 6, o = threadIdx.x & 63;
  __shared__ float xr[256];
  xr[threadIdx.x] = x[(size_t)n * 256 + threadIdx.x];
  __syncthreads();
  float acc = 0.f;
  if (o < 3) {
    const float* __restrict__ Wh = W + (size_t)head * 256 * 3;
#pragma unroll 4
    for (int k = 0; k < 256; k++) acc = fmaf(xr[k], Wh[k * 3 + o], acc);
    h2[((size_t)head * N + n) * 3 + o] = acc;
  }
  float p1 = (o < 3) ? acc * a[head * 6 + o] : 0.f;
  float p2 = (o < 3) ? acc * a[head * 6 + 3 + o] : 0.f;
  for (int s = 32; s; s >>= 1) { p1 += __shfl_xor(p1, s); p2 += __shfl_xor(p2, s); }
  if (o == 0) { s1[head * N + n] = p1; s2[head * N + n] = p2; }
}

// ---------------- per-row softmax stats for ALL heads in one adjacency pass ----------------
__global__ void stats_kernel(const float* __restrict__ s1, const float* __restrict__ s2,
                             const unsigned long long* __restrict__ mask,
                             float* __restrict__ mout, float* __restrict__ dout) {
  const int p = blockIdx.x, t = threadIdx.x;
  const int wave = t >> 6, lane = t & 63;
  __shared__ float red[4][4]; // [wave][head]
  float s2p[4], mx[4];
#pragma unroll
  for (int hh = 0; hh < 4; hh++) { s2p[hh] = s2[hh * N + p]; mx[hh] = -3.4e38f; }
#pragma unroll
  for (int k = 0; k < 8; k++) {
    int q = t + 256 * k;
    unsigned long long mwd = mask[(size_t)p * NW + (q >> 6)];
    if ((mwd >> (q & 63)) & 1ull) {
#pragma unroll
      for (int hh = 0; hh < 4; hh++) mx[hh] = fmaxf(mx[hh], s1[hh * N + q]);
    }
  }
#pragma unroll
  for (int hh = 0; hh < 4; hh++)
    for (int s = 32; s; s >>= 1) mx[hh] = fmaxf(mx[hh], __shfl_xor(mx[hh], s));
  if (lane == 0) {
#pragma unroll
    for (int hh = 0; hh < 4; hh++) red[wave][hh] = mx[hh];
  }
  __syncthreads();
  float m[4];
#pragma unroll
  for (int hh = 0; hh < 4; hh++) {
    float v = fmaxf(fmaxf(red[0][hh], red[1][hh]), fmaxf(red[2][hh], red[3][hh]));
    float e = v + s2p[hh];
    m[hh] = fmaxf(e, ALPHA * e); // lrelu is monotone
  }
  __syncthreads();
  float sm[4] = {0.f, 0.f, 0.f, 0.f};
#pragma unroll
  for (int k = 0; k < 8; k++) {
    int q = t + 256 * k;
    unsigned long long mwd = mask[(size_t)p * NW + (q >> 6)];
    if ((mwd >> (q & 63)) & 1ull) {
#pragma unroll
      for (int hh = 0; hh < 4; hh++) {
        float e = s1[hh * N + q] + s2p[hh];
        e = fmaxf(e, ALPHA * e);
        sm[hh] += __expf(e - m[hh]);
      }
    }
  }
#pragma unroll
  for (int hh = 0; hh < 4; hh++)
    for (int s = 32; s; s >>= 1) sm[hh] += __shfl_xor(sm[hh], s);
  if (lane == 0) {
#pragma unroll
    for (int hh = 0; hh < 4; hh++) red[wave][hh] = sm[hh];
  }
  __syncthreads();
  if (t < 4) {
    dout[t * N + p] = red[0][t] + red[1][t] + red[2][t] + red[3][t];
    mout[t * N + p] = m[t];
  }
}

// ---------------- aggregation: p=lane, acc over full f in regs, no LDS in main loop ----------------
// grid (N/64, H, QS), block 256 = 4 waves (q-split). hp must be zeroed; accumulated atomically.
__global__ void __launch_bounds__(256, 4)
agg_kernel(const float* __restrict__ h, const float* __restrict__ s1,
           const float* __restrict__ s2, const float* __restrict__ mrow,
           const unsigned long long* __restrict__ mask, float* __restrict__ hp) {
  const int p0 = blockIdx.x * 64, head = blockIdx.y;
  const int wave = threadIdx.x >> 6, lane = threadIdx.x & 63;
  const int p = p0 + lane;
  __shared__ float red[64][65];
  const float* __restrict__ hh = h + (size_t)head * N * 64;
  const float* __restrict__ s1h = s1 + head * N;
  const float s2p = s2[head * N + p];
  const float mp = mrow[head * N + p];
  const int qb = blockIdx.z * (N / QS) + wave * (N / QS / 4); // 64 consecutive q per wave
  const unsigned long long mw = mask[(size_t)p * NW + (qb >> 6)];
  float acc[64];
#pragma unroll
  for (int f = 0; f < 64; f++) acc[f] = 0.f;
#pragma unroll 4
  for (int qq = 0; qq < 64; ++qq) {
    const int q = __builtin_amdgcn_readfirstlane(qb + qq);
    float e = s1h[q] + s2p;
    e = fmaxf(e, ALPHA * e);
    float w = ((mw >> qq) & 1ull) ? __expf(e - mp) : 0.f;
    const float4* __restrict__ hq = (const float4*)(hh + (size_t)q * 64);
#pragma unroll
    for (int f4 = 0; f4 < 16; ++f4) {
      float4 hv = hq[f4];
      acc[4 * f4 + 0] = fmaf(w, hv.x, acc[4 * f4 + 0]);
      acc[4 * f4 + 1] = fmaf(w, hv.y, acc[4 * f4 + 1]);
      acc[4 * f4 + 2] = fmaf(w, hv.z, acc[4 * f4 + 2]);
      acc[4 * f4 + 3] = fmaf(w, hv.w, acc[4 * f4 + 3]);
    }
  }
  // cross-wave reduction (pad-65: lane-major writes are conflict-free)
  __syncthreads();
  if (wave == 0) {
#pragma unroll
    for (int f = 0; f < 64; f++) red[lane][f] = acc[f];
  }
  __syncthreads();
  if (wave == 1) {
#pragma unroll
    for (int f = 0; f < 64; f++) red[lane][f] += acc[f];
  }
  __syncthreads();
  if (wave == 2) {
#pragma unroll
    for (int f = 0; f < 64; f++) red[lane][f] += acc[f];
  }
  __syncthreads();
  if (wave == 3) {
#pragma unroll
    for (int f = 0; f < 64; f++) red[lane][f] += acc[f];
  }
  __syncthreads();
  float* __restrict__ hpb = hp + ((size_t)head * N + p0) * 64;
  for (int k = threadIdx.x; k < 4096; k += 256)
    unsafeAtomicAdd(&hpb[k], red[k >> 6][k & 63]);
}

// ---------------- epilogue: normalize, ELU, concat layout ----------------
__global__ void concat_elu_kernel(const float* __restrict__ hp, const float* __restrict__ denom,
                                  float* __restrict__ xout) {
  int idx = blockIdx.x * 256 + threadIdx.x; // H*N*64
  int f = idx & 63;
  int n = (idx >> 6) & (N - 1);
  int head = idx >> 17;
  float v = hp[idx] / denom[head * N + n];
  v = v > 0.f ? v : (__expf(v) - 1.f);
  xout[(size_t)n * (H * 64) + head * 64 + f] = v;
}

// ---------------- layer-2 aggregation (F=3) ----------------
__global__ void agg2_kernel(const float* __restrict__ h2, const float* __restrict__ s1,
                            const float* __restrict__ s2, const float* __restrict__ mrow,
                            const float* __restrict__ drow, const unsigned long long* __restrict__ mask,
                            float* __restrict__ hp2) {
  int p = blockIdx.x, head = blockIdx.y;
  const float* __restrict__ s1h = s1 + head * N;
  float s2p = s2[head * N + p];
  float m = mrow[head * N + p];
  float a0 = 0, a1 = 0, a2 = 0;
  for (int q = threadIdx.x; q < N; q += 256) {
    unsigned long long mwd = mask[(size_t)p * NW + (q >> 6)];
    if ((mwd >> (q & 63)) & 1ull) {
      float e = s1h[q] + s2p;
      e = fmaxf(e, ALPHA * e);
      float w = __expf(e - m);
      const float* hq = h2 + ((size_t)head * N + q) * 3;
      a0 = fmaf(w, hq[0], a0); a1 = fmaf(w, hq[1], a1); a2 = fmaf(w, hq[2], a2);
    }
  }
  for (int s = 32; s; s >>= 1) {
    a0 += __shfl_xor(a0, s); a1 += __shfl_xor(a1, s); a2 += __shfl_xor(a2, s);
  }
  __shared__ float red[4][3];
  int wid = threadIdx.x >> 6;
  if ((threadIdx.x & 63) == 0) { red[wid][0] = a0; red[wid][1] = a1; red[wid][2] = a2; }
  __syncthreads();
  if (threadIdx.x < 3) {
    float v = red[0][threadIdx.x] + red[1][threadIdx.x] + red[2][threadIdx.x] + red[3][threadIdx.x];
    hp2[((size_t)head * N + p) * 3 + threadIdx.x] = v / drow[head * N + p];
  }
}

// ---------------- emb = elu(mean over heads) ----------------
__global__ void emb_kernel(const float* __restrict__ hp2, float* __restrict__ emb) {
  int idx = blockIdx.x * 256 + threadIdx.x; // N*3
  if (idx >= N * 3) return;
  float v = 0.25f * (hp2[idx] + hp2[N * 3 + idx] + hp2[2 * N * 3 + idx] + hp2[3 * N * 3 + idx]);
  v = v > 0.f ? v : (__expf(v) - 1.f);
  emb[idx] = v;
}

// ---------------- all-pairs edge classifier ----------------
__global__ void cls_kernel(const float* __restrict__ emb,
                           const float* __restrict__ W1, const float* __restrict__ b1,
                           const float* __restrict__ W2, const float* __restrict__ b2,
                           float* __restrict__ out) {
  int q = blockIdx.x * 256 + threadIdx.x;
  int p0 = blockIdx.y * 8;
  __shared__ float ep[8][3];
  __shared__ float w1s[96], b1s[32], w2s[32];
  __shared__ float b2s;
  int t = threadIdx.x;
  if (t < 96) w1s[t] = W1[t];
  else if (t < 128) b1s[t - 96] = b1[t - 96];
  else if (t < 160) w2s[t - 128] = W2[t - 128];
  else if (t == 160) b2s = b2[0];
  else if (t >= 192 && t < 216) ((float*)ep)[t - 192] = emb[p0 * 3 + t - 192];
  __syncthreads();
  float e0 = emb[q * 3 + 0], e1 = emb[q * 3 + 1], e2 = emb[q * 3 + 2];
  float d[8][3];
#pragma unroll
  for (int i = 0; i < 8; i++) {
    d[i][0] = fabsf(ep[i][0] - e0);
    d[i][1] = fabsf(ep[i][1] - e1);
    d[i][2] = fabsf(ep[i][2] - e2);
  }
  float acc[8] = {0, 0, 0, 0, 0, 0, 0, 0};
#pragma unroll
  for (int j = 0; j < 32; j++) {
    float c0 = w1s[j], c1 = w1s[32 + j], c2 = w1s[64 + j], bb = b1s[j], w2 = w2s[j];
#pragma unroll
    for (int i = 0; i < 8; i++) {
      float hv = fmaxf(bb + d[i][0] * c0 + d[i][1] * c1 + d[i][2] * c2, 0.f);
      acc[i] += hv * w2;
    }
  }
#pragma unroll
  for (int i = 0; i < 8; i++) {
    float x = acc[i] + b2s;
    out[(size_t)(p0 + i) * N + q] = 1.f / (1.f + __expf(-x));
  }
}

extern "C" void kernel_launch(void* const* d_in, const int* in_sizes, int n_in,
                              void* d_out, int out_size, void* d_ws, size_t ws_size,
                              hipStream_t stream) {
  const float* nf    = (const float*)d_in[0];
  const int*   adj   = (const int*)d_in[1];
  const float* encW1 = (const float*)d_in[2];
  const float* encb1 = (const float*)d_in[3];
  const float* encW2 = (const float*)d_in[4];
  const float* encb2 = (const float*)d_in[5];
  const float* gatW0 = (const float*)d_in[6];
  const float* gata0 = (const float*)d_in[7];
  const float* gatW1 = (const float*)d_in[8];
  const float* gata1 = (const float*)d_in[9];
  const float* gatW2 = (const float*)d_in[10];
  const float* gata2 = (const float*)d_in[11];
  const float* clsW1 = (const float*)d_in[12];
  const float* clsb1 = (const float*)d_in[13];
  const float* clsW2 = (const float*)d_in[14];
  const float* clsb2 = (const float*)d_in[15];

  float* ws = (float*)d_ws;
  float* x0  = ws;                    // 2048*64
  float* h   = x0 + 131072;           // H*N*64
  float* s1  = h + 524288;            // H*N
  float* s2  = s1 + 8192;
  float* m   = s2 + 8192;
  float* dn  = m + 8192;
  float* xA  = dn + 8192;             // 2048*256
  float* xB  = xA + 524288;           // 2048*256
  float* hp  = xB + 524288;           // H*N*64 accumulator
  float* h2  = hp + 524288;           // H*N*3
  float* hp2 = h2 + 24576;            // H*N*3
  unsigned long long* mask = (unsigned long long*)(hp2 + 24576); // N*NW words (512 KB)

  float* emb = (float*)d_out;         // 2048*3
  float* eprob = emb + N * 3;         // 2048*2048

  pack_adj_kernel<<<dim3(N * NW / 4), dim3(256), 0, stream>>>(adj, mask);
  enc_kernel<<<dim3(N), dim3(64), 0, stream>>>(nf, encW1, encb1, encW2, encb2, x0);

  // ---- GAT layer 0 (in_f=64) ----
  h_all_kernel<<<dim3(N / 4), dim3(256), 4 * 64 * sizeof(float), stream>>>(x0, gatW0, gata0, h, s1, s2, 64);
  stats_kernel<<<dim3(N), dim3(256), 0, stream>>>(s1, s2, mask, m, dn);
  hipMemsetAsync(hp, 0, (size_t)H * N * 64 * sizeof(float), stream);
  agg_kernel<<<dim3(N / 64, H, QS), dim3(256), 0, stream>>>(h, s1, s2, m, mask, hp);
  concat_elu_kernel<<<dim3(H * N * 64 / 256), dim3(256), 0, stream>>>(hp, dn, xA);

  // ---- GAT layer 1 (in_f=256) ----
  h_all_kernel<<<dim3(N / 4), dim3(256), 4 * 256 * sizeof(float), stream>>>(xA, gatW1, gata1, h, s1, s2, 256);
  stats_kernel<<<dim3(N), dim3(256), 0, stream>>>(s1, s2, mask, m, dn);
  hipMemsetAsync(hp, 0, (size_t)H * N * 64 * sizeof(float), stream);
  agg_kernel<<<dim3(N / 64, H, QS), dim3(256), 0, stream>>>(h, s1, s2, m, mask, hp);
  concat_elu_kernel<<<dim3(H * N * 64 / 256), dim3(256), 0, stream>>>(hp, dn, xB);

  // ---- GAT layer 2 (in_f=256, F_out=3, mean over heads) ----
  h3_kernel<<<dim3(N), dim3(256), 0, stream>>>(xB, gatW2, gata2, h2, s1, s2);
  stats_kernel<<<dim3(N), dim3(256), 0, stream>>>(s1, s2, mask, m, dn);
  agg2_kernel<<<dim3(N, H), dim3(256), 0, stream>>>(h2, s1, s2, m, dn, mask, hp2);
  emb_kernel<<<dim3((N * 3 + 255) / 256), dim3(256), 0, stream>>>(hp2, emb);

  // ---- classifier ----
  cls_kernel<<<dim3(8, N / 8), dim3(256), 0, stream>>>(emb, clsW1, clsb1, clsW2, clsb2, eprob);
}

// Round 3
// 252.974 us; speedup vs baseline: 1.7667x; 1.0148x over previous
//
#include <hip/hip_runtime.h>
#include <hip/hip_bf16.h>

#define ALPHA 0.2f
constexpr int N = 2048;
constexpr int H = 4;
constexpr int QS = 4;      // q-splits in agg kernel
constexpr int NW = N / 64; // 32 mask words per row

typedef __attribute__((ext_vector_type(8))) short short8v;  // bf16 bits x8 (4 VGPR)
typedef __attribute__((ext_vector_type(4))) float f32x4;

__device__ inline unsigned short bf16_rne(float f) {
  unsigned u = __float_as_uint(f);
  return (unsigned short)((u + 0x7fffu + ((u >> 16) & 1u)) >> 16);
}

// ---------------- pack adjacency into bitmask ----------------
__global__ void pack_adj_kernel(const int* __restrict__ adj, unsigned long long* __restrict__ mask) {
  int word = blockIdx.x * 4 + (threadIdx.x >> 6);
  int lane = threadIdx.x & 63;
  unsigned long long b = __ballot(adj[(size_t)word * 64 + lane] != 0);
  if (lane == 0) mask[word] = b;
}

// ---------------- encoder ----------------
__global__ void enc_kernel(const float* __restrict__ nf,
                           const float* __restrict__ W1, const float* __restrict__ b1,
                           const float* __restrict__ W2, const float* __restrict__ b2,
                           float* __restrict__ x0) {
  int n = blockIdx.x;
  int j = threadIdx.x; // 64
  __shared__ float row[10];
  __shared__ float x1[64];
  if (j < 10) row[j] = nf[n * 10 + j];
  __syncthreads();
  float acc = b1[j];
#pragma unroll
  for (int k = 0; k < 10; k++) acc += row[k] * W1[k * 64 + j];
  x1[j] = fmaxf(acc, 0.f);
  __syncthreads();
  float acc2 = b2[j];
#pragma unroll
  for (int k = 0; k < 64; k++) acc2 += x1[k] * W2[k * 64 + j];
  x0[n * 64 + j] = acc2;
}

// ---------------- projection h = x@W for all 4 heads, 4 nodes/block; also s1,s2 ----------------
__global__ void h_all_kernel(const float* __restrict__ x, const float* __restrict__ W,
                             const float* __restrict__ a, float* __restrict__ h,
                             float* __restrict__ s1, float* __restrict__ s2, int in_f) {
  const int n0 = blockIdx.x * 4;
  const int head = threadIdx.x >> 6, o = threadIdx.x & 63;
  extern __shared__ float xr[]; // 4 * in_f
  for (int k = threadIdx.x; k < 4 * in_f; k += 256) xr[k] = x[(size_t)n0 * in_f + k];
  __syncthreads();
  const float* __restrict__ Wh = W + (size_t)head * in_f * 64;
  float acc[4] = {0.f, 0.f, 0.f, 0.f};
#pragma unroll 4
  for (int k = 0; k < in_f; k++) {
    float wv = Wh[k * 64 + o];
    acc[0] = fmaf(xr[k], wv, acc[0]);
    acc[1] = fmaf(xr[in_f + k], wv, acc[1]);
    acc[2] = fmaf(xr[2 * in_f + k], wv, acc[2]);
    acc[3] = fmaf(xr[3 * in_f + k], wv, acc[3]);
  }
  const float aa1 = a[head * 128 + o];
  const float aa2 = a[head * 128 + 64 + o];
#pragma unroll
  for (int j = 0; j < 4; j++) {
    h[((size_t)head * N + n0 + j) * 64 + o] = acc[j];
    float p1 = acc[j] * aa1, p2 = acc[j] * aa2;
    for (int s = 32; s; s >>= 1) { p1 += __shfl_xor(p1, s); p2 += __shfl_xor(p2, s); }
    if (o == 0) { s1[head * N + n0 + j] = p1; s2[head * N + n0 + j] = p2; }
  }
}

// ---------------- transpose h -> bf16 hi/lo [head][f][q] ----------------
__global__ void htrans_kernel(const float* __restrict__ h,
                              __hip_bfloat16* __restrict__ hT_hi,
                              __hip_bfloat16* __restrict__ hT_lo) {
  const int head = blockIdx.y, q0 = blockIdx.x * 64;
  __shared__ float tile[64][65];
  const float* __restrict__ hh = h + ((size_t)head * N + q0) * 64;
#pragma unroll
  for (int k = 0; k < 16; k++) {
    int idx = threadIdx.x + 256 * k;
    int q = idx >> 6, f = idx & 63;
    tile[q][f] = hh[q * 64 + f];
  }
  __syncthreads();
#pragma unroll
  for (int k = 0; k < 16; k++) {
    int idx = threadIdx.x + 256 * k;
    int qq = idx & 63, f = idx >> 6; // f in 0..63 over k loop: (idx>>6) = k*4 + tid>>6
    float v = tile[qq][f];
    unsigned short hb = bf16_rne(v);
    float hf = __uint_as_float((unsigned)hb << 16);
    unsigned short lb = bf16_rne(v - hf);
    size_t oidx = ((size_t)head * 64 + f) * N + q0 + qq;
    *(unsigned short*)&hT_hi[oidx] = hb;
    *(unsigned short*)&hT_lo[oidx] = lb;
  }
}

// ---------------- per-row softmax stats for ALL heads ----------------
__global__ void stats_kernel(const float* __restrict__ s1, const float* __restrict__ s2,
                             const unsigned long long* __restrict__ mask,
                             float* __restrict__ mout, float* __restrict__ dout) {
  const int p = blockIdx.x, t = threadIdx.x;
  const int wave = t >> 6, lane = t & 63;
  __shared__ float red[4][4];
  float s2p[4], mx[4];
#pragma unroll
  for (int hh = 0; hh < 4; hh++) { s2p[hh] = s2[hh * N + p]; mx[hh] = -3.4e38f; }
#pragma unroll
  for (int k = 0; k < 8; k++) {
    int q = t + 256 * k;
    unsigned long long mwd = mask[(size_t)p * NW + (q >> 6)];
    if ((mwd >> (q & 63)) & 1ull) {
#pragma unroll
      for (int hh = 0; hh < 4; hh++) mx[hh] = fmaxf(mx[hh], s1[hh * N + q]);
    }
  }
#pragma unroll
  for (int hh = 0; hh < 4; hh++)
    for (int s = 32; s; s >>= 1) mx[hh] = fmaxf(mx[hh], __shfl_xor(mx[hh], s));
  if (lane == 0) {
#pragma unroll
    for (int hh = 0; hh < 4; hh++) red[wave][hh] = mx[hh];
  }
  __syncthreads();
  float m[4];
#pragma unroll
  for (int hh = 0; hh < 4; hh++) {
    float v = fmaxf(fmaxf(red[0][hh], red[1][hh]), fmaxf(red[2][hh], red[3][hh]));
    float e = v + s2p[hh];
    m[hh] = fmaxf(e, ALPHA * e);
  }
  __syncthreads();
  float sm[4] = {0.f, 0.f, 0.f, 0.f};
#pragma unroll
  for (int k = 0; k < 8; k++) {
    int q = t + 256 * k;
    unsigned long long mwd = mask[(size_t)p * NW + (q >> 6)];
    if ((mwd >> (q & 63)) & 1ull) {
#pragma unroll
      for (int hh = 0; hh < 4; hh++) {
        float e = s1[hh * N + q] + s2p[hh];
        e = fmaxf(e, ALPHA * e);
        sm[hh] += __expf(e - m[hh]);
      }
    }
  }
#pragma unroll
  for (int hh = 0; hh < 4; hh++)
    for (int s = 32; s; s >>= 1) sm[hh] += __shfl_xor(sm[hh], s);
  if (lane == 0) {
#pragma unroll
    for (int hh = 0; hh < 4; hh++) red[wave][hh] = sm[hh];
  }
  __syncthreads();
  if (t < 4) {
    dout[t * N + p] = red[0][t] + red[1][t] + red[2][t] + red[3][t];
    mout[t * N + p] = m[t];
  }
}

// ---------------- MFMA aggregation ----------------
// grid (N/64, H, QS), block 256 = 4 waves. Wave wid owns p-frag [p0+16*wid, +16),
// full f (4 frags), K-chunk = N/QS q. hp (fp32 [H][N][64]) must be zeroed.
// w = exp(lrelu(s1[q]+s2[p]) - m[p]) masked; bf16 hi/lo split, 3-term MFMA.
__global__ void __launch_bounds__(256, 2)
agg_mfma_kernel(const __hip_bfloat16* __restrict__ hT_hi, const __hip_bfloat16* __restrict__ hT_lo,
                const float* __restrict__ s1, const float* __restrict__ s2,
                const float* __restrict__ mrow, const unsigned long long* __restrict__ mask,
                float* __restrict__ hp) {
  const int head = blockIdx.y;
  const int p0 = blockIdx.x * 64;
  const int wid = threadIdx.x >> 6, lane = threadIdx.x & 63;
  const int col = lane & 15, kgrp = lane >> 4;
  const int p = p0 + wid * 16 + col; // A-operand row for this lane
  const float s2p = s2[head * N + p];
  const float mp = mrow[head * N + p];
  const float* __restrict__ s1h = s1 + head * N;
  const unsigned long long* __restrict__ mr = mask + (size_t)p * NW;

  // B row base offsets for the 4 f-frags (col = lane&15 is also the B column)
  size_t boff[4];
#pragma unroll
  for (int ff = 0; ff < 4; ff++) boff[ff] = ((size_t)head * 64 + ff * 16 + col) * N;

  f32x4 acc[4] = {{0,0,0,0},{0,0,0,0},{0,0,0,0},{0,0,0,0}};
  const int qbase = blockIdx.z * (N / QS);

  for (int ks = 0; ks < (N / QS) / 32; ++ks) {
    const int q0 = qbase + ks * 32;
    const int qa = q0 + kgrp * 8;
    // load 8 s1 values for this lane's k-slice
    float4 s1v0 = *(const float4*)(s1h + qa);
    float4 s1v1 = *(const float4*)(s1h + qa + 4);
    unsigned long long mwd = mr[q0 >> 6];
    unsigned b8 = (unsigned)((mwd >> ((q0 & 63) + kgrp * 8)) & 0xFFull);
    float sv[8] = {s1v0.x, s1v0.y, s1v0.z, s1v0.w, s1v1.x, s1v1.y, s1v1.z, s1v1.w};
    short8v a_hi, a_lo;
#pragma unroll
    for (int e = 0; e < 8; e++) {
      float ev = sv[e] + s2p;
      float lr = fmaxf(ev, ALPHA * ev);
      float w = ((b8 >> e) & 1u) ? __expf(lr - mp) : 0.f;
      unsigned short hb = bf16_rne(w);
      float hf = __uint_as_float((unsigned)hb << 16);
      unsigned short lb = bf16_rne(w - hf);
      a_hi[e] = (short)hb;
      a_lo[e] = (short)lb;
    }
#pragma unroll
    for (int ff = 0; ff < 4; ff++) {
      short8v b_hi = *(const short8v*)(hT_hi + boff[ff] + qa);
      short8v b_lo = *(const short8v*)(hT_lo + boff[ff] + qa);
      acc[ff] = __builtin_amdgcn_mfma_f32_16x16x32_bf16(a_hi, b_hi, acc[ff], 0, 0, 0);
      acc[ff] = __builtin_amdgcn_mfma_f32_16x16x32_bf16(a_lo, b_hi, acc[ff], 0, 0, 0);
      acc[ff] = __builtin_amdgcn_mfma_f32_16x16x32_bf16(a_hi, b_lo, acc[ff], 0, 0, 0);
    }
  }
  // epilogue: D layout col=lane&15, row=(lane>>4)*4+r
  float* __restrict__ hpb = hp + ((size_t)head * N + p0 + wid * 16) * 64;
#pragma unroll
  for (int ff = 0; ff < 4; ff++) {
#pragma unroll
    for (int r = 0; r < 4; r++) {
      unsafeAtomicAdd(&hpb[(kgrp * 4 + r) * 64 + ff * 16 + col], acc[ff][r]);
    }
  }
}

// ---------------- epilogue: normalize, ELU, concat layout ----------------
__global__ void concat_elu_kernel(const float* __restrict__ hp, const float* __restrict__ denom,
                                  float* __restrict__ xout) {
  int idx = blockIdx.x * 256 + threadIdx.x; // H*N*64
  int f = idx & 63;
  int n = (idx >> 6) & (N - 1);
  int head = idx >> 17;
  float v = hp[idx] / denom[head * N + n];
  v = v > 0.f ? v : (__expf(v) - 1.f);
  xout[(size_t)n * (H * 64) + head * 64 + f] = v;
}

// ---------------- layer-2 projection (F_out=3) ----------------
__global__ void h3_kernel(const float* __restrict__ x, const float* __restrict__ W,
                          const float* __restrict__ a, float* __restrict__ h2,
                          float* __restrict__ s1, float* __restrict__ s2) {
  const int n = blockIdx.x;
  const int head = threadIdx.x >> 6, o = threadIdx.x & 63;
  __shared__ float xr[256];
  xr[threadIdx.x] = x[(size_t)n * 256 + threadIdx.x];
  __syncthreads();
  float acc = 0.f;
  if (o < 3) {
    const float* __restrict__ Wh = W + (size_t)head * 256 * 3;
#pragma unroll 4
    for (int k = 0; k < 256; k++) acc = fmaf(xr[k], Wh[k * 3 + o], acc);
    h2[((size_t)head * N + n) * 3 + o] = acc;
  }
  float p1 = (o < 3) ? acc * a[head * 6 + o] : 0.f;
  float p2 = (o < 3) ? acc * a[head * 6 + 3 + o] : 0.f;
  for (int s = 32; s; s >>= 1) { p1 += __shfl_xor(p1, s); p2 += __shfl_xor(p2, s); }
  if (o == 0) { s1[head * N + n] = p1; s2[head * N + n] = p2; }
}

// ---------------- layer-2 aggregation (F=3) ----------------
__global__ void agg2_kernel(const float* __restrict__ h2, const float* __restrict__ s1,
                            const float* __restrict__ s2, const float* __restrict__ mrow,
                            const float* __restrict__ drow, const unsigned long long* __restrict__ mask,
                            float* __restrict__ hp2) {
  int p = blockIdx.x, head = blockIdx.y;
  const float* __restrict__ s1h = s1 + head * N;
  float s2p = s2[head * N + p];
  float m = mrow[head * N + p];
  float a0 = 0, a1 = 0, a2 = 0;
  for (int q = threadIdx.x; q < N; q += 256) {
    unsigned long long mwd = mask[(size_t)p * NW + (q >> 6)];
    if ((mwd >> (q & 63)) & 1ull) {
      float e = s1h[q] + s2p;
      e = fmaxf(e, ALPHA * e);
      float w = __expf(e - m);
      const float* hq = h2 + ((size_t)head * N + q) * 3;
      a0 = fmaf(w, hq[0], a0); a1 = fmaf(w, hq[1], a1); a2 = fmaf(w, hq[2], a2);
    }
  }
  for (int s = 32; s; s >>= 1) {
    a0 += __shfl_xor(a0, s); a1 += __shfl_xor(a1, s); a2 += __shfl_xor(a2, s);
  }
  __shared__ float red[4][3];
  int wid = threadIdx.x >> 6;
  if ((threadIdx.x & 63) == 0) { red[wid][0] = a0; red[wid][1] = a1; red[wid][2] = a2; }
  __syncthreads();
  if (threadIdx.x < 3) {
    float v = red[0][threadIdx.x] + red[1][threadIdx.x] + red[2][threadIdx.x] + red[3][threadIdx.x];
    hp2[((size_t)head * N + p) * 3 + threadIdx.x] = v / drow[head * N + p];
  }
}

// ---------------- emb = elu(mean over heads) ----------------
__global__ void emb_kernel(const float* __restrict__ hp2, float* __restrict__ emb) {
  int idx = blockIdx.x * 256 + threadIdx.x; // N*3
  if (idx >= N * 3) return;
  float v = 0.25f * (hp2[idx] + hp2[N * 3 + idx] + hp2[2 * N * 3 + idx] + hp2[3 * N * 3 + idx]);
  v = v > 0.f ? v : (__expf(v) - 1.f);
  emb[idx] = v;
}

// ---------------- all-pairs edge classifier ----------------
__global__ void cls_kernel(const float* __restrict__ emb,
                           const float* __restrict__ W1, const float* __restrict__ b1,
                           const float* __restrict__ W2, const float* __restrict__ b2,
                           float* __restrict__ out) {
  int q = blockIdx.x * 256 + threadIdx.x;
  int p0 = blockIdx.y * 8;
  __shared__ float ep[8][3];
  __shared__ float w1s[96], b1s[32], w2s[32];
  __shared__ float b2s;
  int t = threadIdx.x;
  if (t < 96) w1s[t] = W1[t];
  else if (t < 128) b1s[t - 96] = b1[t - 96];
  else if (t < 160) w2s[t - 128] = W2[t - 128];
  else if (t == 160) b2s = b2[0];
  else if (t >= 192 && t < 216) ((float*)ep)[t - 192] = emb[p0 * 3 + t - 192];
  __syncthreads();
  float e0 = emb[q * 3 + 0], e1 = emb[q * 3 + 1], e2 = emb[q * 3 + 2];
  float d[8][3];
#pragma unroll
  for (int i = 0; i < 8; i++) {
    d[i][0] = fabsf(ep[i][0] - e0);
    d[i][1] = fabsf(ep[i][1] - e1);
    d[i][2] = fabsf(ep[i][2] - e2);
  }
  float acc[8] = {0, 0, 0, 0, 0, 0, 0, 0};
#pragma unroll
  for (int j = 0; j < 32; j++) {
    float c0 = w1s[j], c1 = w1s[32 + j], c2 = w1s[64 + j], bb = b1s[j], w2 = w2s[j];
#pragma unroll
    for (int i = 0; i < 8; i++) {
      float hv = fmaxf(bb + d[i][0] * c0 + d[i][1] * c1 + d[i][2] * c2, 0.f);
      acc[i] += hv * w2;
    }
  }
#pragma unroll
  for (int i = 0; i < 8; i++) {
    float x = acc[i] + b2s;
    out[(size_t)(p0 + i) * N + q] = 1.f / (1.f + __expf(-x));
  }
}

extern "C" void kernel_launch(void* const* d_in, const int* in_sizes, int n_in,
                              void* d_out, int out_size, void* d_ws, size_t ws_size,
                              hipStream_t stream) {
  const float* nf    = (const float*)d_in[0];
  const int*   adj   = (const int*)d_in[1];
  const float* encW1 = (const float*)d_in[2];
  const float* encb1 = (const float*)d_in[3];
  const float* encW2 = (const float*)d_in[4];
  const float* encb2 = (const float*)d_in[5];
  const float* gatW0 = (const float*)d_in[6];
  const float* gata0 = (const float*)d_in[7];
  const float* gatW1 = (const float*)d_in[8];
  const float* gata1 = (const float*)d_in[9];
  const float* gatW2 = (const float*)d_in[10];
  const float* gata2 = (const float*)d_in[11];
  const float* clsW1 = (const float*)d_in[12];
  const float* clsb1 = (const float*)d_in[13];
  const float* clsW2 = (const float*)d_in[14];
  const float* clsb2 = (const float*)d_in[15];

  float* ws = (float*)d_ws;
  float* x0  = ws;                    // 2048*64
  float* h   = x0 + 131072;           // H*N*64
  float* s1  = h + 524288;            // H*N
  float* s2  = s1 + 8192;
  float* m   = s2 + 8192;
  float* dn  = m + 8192;
  float* xA  = dn + 8192;             // 2048*256
  float* xB  = xA + 524288;           // 2048*256 (layer-1 output; reused as hT before it's written)
  float* hp  = xB + 524288;           // H*N*64 accumulator
  float* h2  = hp + 524288;           // H*N*3
  float* hp2 = h2 + 24576;            // H*N*3
  unsigned long long* mask = (unsigned long long*)(hp2 + 24576); // N*NW words (512 KB)

  // hT hi/lo (bf16 [H][64][N], 512 KB each) overlap xB: dead until concat_elu L1 writes xB
  __hip_bfloat16* hT_hi = (__hip_bfloat16*)xB;
  __hip_bfloat16* hT_lo = (__hip_bfloat16*)(xB + 262144);

  float* emb = (float*)d_out;         // 2048*3
  float* eprob = emb + N * 3;         // 2048*2048

  pack_adj_kernel<<<dim3(N * NW / 4), dim3(256), 0, stream>>>(adj, mask);
  enc_kernel<<<dim3(N), dim3(64), 0, stream>>>(nf, encW1, encb1, encW2, encb2, x0);

  // ---- GAT layer 0 (in_f=64) ----
  h_all_kernel<<<dim3(N / 4), dim3(256), 4 * 64 * sizeof(float), stream>>>(x0, gatW0, gata0, h, s1, s2, 64);
  htrans_kernel<<<dim3(N / 64, H), dim3(256), 0, stream>>>(h, hT_hi, hT_lo);
  stats_kernel<<<dim3(N), dim3(256), 0, stream>>>(s1, s2, mask, m, dn);
  hipMemsetAsync(hp, 0, (size_t)H * N * 64 * sizeof(float), stream);
  agg_mfma_kernel<<<dim3(N / 64, H, QS), dim3(256), 0, stream>>>(hT_hi, hT_lo, s1, s2, m, mask, hp);
  concat_elu_kernel<<<dim3(H * N * 64 / 256), dim3(256), 0, stream>>>(hp, dn, xA);

  // ---- GAT layer 1 (in_f=256) ----
  h_all_kernel<<<dim3(N / 4), dim3(256), 4 * 256 * sizeof(float), stream>>>(xA, gatW1, gata1, h, s1, s2, 256);
  htrans_kernel<<<dim3(N / 64, H), dim3(256), 0, stream>>>(h, hT_hi, hT_lo);
  stats_kernel<<<dim3(N), dim3(256), 0, stream>>>(s1, s2, mask, m, dn);
  hipMemsetAsync(hp, 0, (size_t)H * N * 64 * sizeof(float), stream);
  agg_mfma_kernel<<<dim3(N / 64, H, QS), dim3(256), 0, stream>>>(hT_hi, hT_lo, s1, s2, m, mask, hp);
  concat_elu_kernel<<<dim3(H * N * 64 / 256), dim3(256), 0, stream>>>(hp, dn, xB);

  // ---- GAT layer 2 (in_f=256, F_out=3, mean over heads) ----
  h3_kernel<<<dim3(N), dim3(256), 0, stream>>>(xB, gatW2, gata2, h2, s1, s2);
  stats_kernel<<<dim3(N), dim3(256), 0, stream>>>(s1, s2, mask, m, dn);
  agg2_kernel<<<dim3(N, H), dim3(256), 0, stream>>>(h2, s1, s2, m, dn, mask, hp2);
  emb_kernel<<<dim3((N * 3 + 255) / 256), dim3(256), 0, stream>>>(hp2, emb);

  // ---- classifier ----
  cls_kernel<<<dim3(8, N / 8), dim3(256), 0, stream>>>(emb, clsW1, clsb1, clsW2, clsb2, eprob);
}

// Round 4
// 162.948 us; speedup vs baseline: 2.7428x; 1.5525x over previous
//
#include <hip/hip_runtime.h>
#include <hip/hip_bf16.h>

#define ALPHA 0.2f
constexpr int N = 2048;
constexpr int H = 4;
constexpr int QS = 8;          // q-splits in agg kernel
constexpr int NW = N / 64;     // 32 mask words per row
constexpr int KITER = (N / QS) / 32; // 8

typedef __attribute__((ext_vector_type(8))) short short8v;  // bf16 bits x8
typedef __attribute__((ext_vector_type(4))) float f32x4;

__device__ inline unsigned short bf16_rne(float f) {
  unsigned u = __float_as_uint(f);
  return (unsigned short)((u + 0x7fffu + ((u >> 16) & 1u)) >> 16);
}

// ---------------- pack adjacency into bitmask ----------------
__global__ void pack_adj_kernel(const int* __restrict__ adj, unsigned long long* __restrict__ mask) {
  int word = blockIdx.x * 4 + (threadIdx.x >> 6);
  int lane = threadIdx.x & 63;
  unsigned long long b = __ballot(adj[(size_t)word * 64 + lane] != 0);
  if (lane == 0) mask[word] = b;
}

// ---------------- fused encoder + layer-0 projection ----------------
// block = 4 nodes, 256 threads. Writes hT (bf16 [H][64][N]), s1, s2.
__global__ void enc_h0_kernel(const float* __restrict__ nf,
                              const float* __restrict__ W1, const float* __restrict__ b1,
                              const float* __restrict__ W2, const float* __restrict__ b2,
                              const float* __restrict__ W0, const float* __restrict__ a0,
                              __hip_bfloat16* __restrict__ hT,
                              float* __restrict__ s1, float* __restrict__ s2) {
  const int n0 = blockIdx.x * 4;
  const int j = threadIdx.x >> 6, o = threadIdx.x & 63; // j doubles as head later
  __shared__ float nfs[4][10];
  __shared__ float x1[4][64];
  __shared__ float xs[4][64];
  if (threadIdx.x < 40) nfs[threadIdx.x / 10][threadIdx.x % 10] = nf[n0 * 10 + threadIdx.x];
  __syncthreads();
  float acc = b1[o];
#pragma unroll
  for (int k = 0; k < 10; k++) acc = fmaf(nfs[j][k], W1[k * 64 + o], acc);
  x1[j][o] = fmaxf(acc, 0.f);
  __syncthreads();
  float acc2 = b2[o];
#pragma unroll 8
  for (int k = 0; k < 64; k++) acc2 = fmaf(x1[j][k], W2[k * 64 + o], acc2);
  xs[j][o] = acc2;
  __syncthreads();
  // projection phase: j = head
  const int head = j;
  const float* __restrict__ Wh = W0 + (size_t)head * 64 * 64;
  float ah[4] = {0.f, 0.f, 0.f, 0.f};
#pragma unroll 8
  for (int k = 0; k < 64; k++) {
    float wv = Wh[k * 64 + o];
    ah[0] = fmaf(xs[0][k], wv, ah[0]);
    ah[1] = fmaf(xs[1][k], wv, ah[1]);
    ah[2] = fmaf(xs[2][k], wv, ah[2]);
    ah[3] = fmaf(xs[3][k], wv, ah[3]);
  }
  const float aa1 = a0[head * 128 + o];
  const float aa2 = a0[head * 128 + 64 + o];
  ushort4 pk;
  unsigned short* pkp = (unsigned short*)&pk;
#pragma unroll
  for (int jj = 0; jj < 4; jj++) {
    pkp[jj] = bf16_rne(ah[jj]);
    float p1 = ah[jj] * aa1, p2 = ah[jj] * aa2;
    for (int s = 32; s; s >>= 1) { p1 += __shfl_xor(p1, s); p2 += __shfl_xor(p2, s); }
    if (o == 0) { s1[head * N + n0 + jj] = p1; s2[head * N + n0 + jj] = p2; }
  }
  *(ushort4*)((unsigned short*)hT + ((size_t)head * 64 + o) * N + n0) = pk;
}

// ---------------- layer-1 projection (in_f=256), writes hT/s1/s2 ----------------
__global__ void h_all_kernel(const float* __restrict__ x, const float* __restrict__ W,
                             const float* __restrict__ a,
                             __hip_bfloat16* __restrict__ hT,
                             float* __restrict__ s1, float* __restrict__ s2) {
  const int n0 = blockIdx.x * 4;
  const int head = threadIdx.x >> 6, o = threadIdx.x & 63;
  __shared__ float xr[4][256];
  for (int k = threadIdx.x; k < 1024; k += 256) xr[k >> 8][k & 255] = x[(size_t)n0 * 256 + k];
  __syncthreads();
  const float* __restrict__ Wh = W + (size_t)head * 256 * 64;
  float ah[4] = {0.f, 0.f, 0.f, 0.f};
#pragma unroll 4
  for (int k = 0; k < 256; k++) {
    float wv = Wh[k * 64 + o];
    ah[0] = fmaf(xr[0][k], wv, ah[0]);
    ah[1] = fmaf(xr[1][k], wv, ah[1]);
    ah[2] = fmaf(xr[2][k], wv, ah[2]);
    ah[3] = fmaf(xr[3][k], wv, ah[3]);
  }
  const float aa1 = a[head * 128 + o];
  const float aa2 = a[head * 128 + 64 + o];
  ushort4 pk;
  unsigned short* pkp = (unsigned short*)&pk;
#pragma unroll
  for (int jj = 0; jj < 4; jj++) {
    pkp[jj] = bf16_rne(ah[jj]);
    float p1 = ah[jj] * aa1, p2 = ah[jj] * aa2;
    for (int s = 32; s; s >>= 1) { p1 += __shfl_xor(p1, s); p2 += __shfl_xor(p2, s); }
    if (o == 0) { s1[head * N + n0 + jj] = p1; s2[head * N + n0 + jj] = p2; }
  }
  *(ushort4*)((unsigned short*)hT + ((size_t)head * 64 + o) * N + n0) = pk;
}

// ---------------- per-head softmax shift: mh = lrelu(max s1 + max s2) ----------------
__global__ void maxred_kernel(const float* __restrict__ s1, const float* __restrict__ s2,
                              float* __restrict__ mh) {
  const int head = blockIdx.x, t = threadIdx.x;
  float m1 = -3.4e38f, m2 = -3.4e38f;
  for (int q = t; q < N; q += 256) {
    m1 = fmaxf(m1, s1[head * N + q]);
    m2 = fmaxf(m2, s2[head * N + q]);
  }
  for (int s = 32; s; s >>= 1) { m1 = fmaxf(m1, __shfl_xor(m1, s)); m2 = fmaxf(m2, __shfl_xor(m2, s)); }
  __shared__ float r1[4], r2[4];
  int w = t >> 6;
  if ((t & 63) == 0) { r1[w] = m1; r2[w] = m2; }
  __syncthreads();
  if (t == 0) {
    float a = fmaxf(fmaxf(r1[0], r1[1]), fmaxf(r1[2], r1[3]));
    float b = fmaxf(fmaxf(r2[0], r2[1]), fmaxf(r2[2], r2[3]));
    float e = a + b;
    mh[head] = fmaxf(e, ALPHA * e);
  }
}

// ---------------- MFMA aggregation + in-kernel denominator ----------------
// grid (N/64, H, QS), block 256 = 4 waves. hp (fp32, zeroed) atomically accumulated.
// dnz[head][z][p] written (no init needed). w = exp(lrelu(s1q+s2p) - mh), hi/lo split A, bf16 B.
__global__ void __launch_bounds__(256, 4)
agg_mfma_kernel(const __hip_bfloat16* __restrict__ hT,
                const float* __restrict__ s1, const float* __restrict__ s2,
                const float* __restrict__ mh, const unsigned long long* __restrict__ mask,
                float* __restrict__ hp, float* __restrict__ dnz) {
  const int head = blockIdx.y;
  const int p0 = blockIdx.x * 64;
  const int wid = threadIdx.x >> 6, lane = threadIdx.x & 63;
  const int col = lane & 15, kgrp = lane >> 4;
  const int p = p0 + wid * 16 + col; // A-operand row for this lane
  const float s2p = s2[head * N + p];
  const float mhv = mh[head];
  const float* __restrict__ s1h = s1 + head * N;
  const int qbase = blockIdx.z * (N / QS);
  // all mask words for this lane's z-chunk (256 q = 4 words)
  const unsigned long long* __restrict__ mr = mask + (size_t)p * NW + (qbase >> 6);
  unsigned long long mw0 = mr[0], mw1 = mr[1], mw2 = mr[2], mw3 = mr[3];

  const unsigned short* __restrict__ hTu = (const unsigned short*)hT;
  size_t boff[4];
#pragma unroll
  for (int ff = 0; ff < 4; ff++) boff[ff] = ((size_t)head * 64 + ff * 16 + col) * N;

  f32x4 acc[4] = {{0,0,0,0},{0,0,0,0},{0,0,0,0},{0,0,0,0}};
  float wsum = 0.f;

#pragma unroll
  for (int ks = 0; ks < KITER; ks++) {
    const int qa = qbase + ks * 32 + kgrp * 8;
    float4 s1v0 = *(const float4*)(s1h + qa);
    float4 s1v1 = *(const float4*)(s1h + qa + 4);
    unsigned long long mwsel = (ks < 2) ? mw0 : (ks < 4) ? mw1 : (ks < 6) ? mw2 : mw3;
    unsigned b8 = (unsigned)((mwsel >> ((ks & 1) * 32 + kgrp * 8)) & 0xFFull);
    float sv[8] = {s1v0.x, s1v0.y, s1v0.z, s1v0.w, s1v1.x, s1v1.y, s1v1.z, s1v1.w};
    short8v a_hi, a_lo;
#pragma unroll
    for (int e = 0; e < 8; e++) {
      float ev = sv[e] + s2p;
      float lr = fmaxf(ev, ALPHA * ev);
      float w = ((b8 >> e) & 1u) ? __expf(lr - mhv) : 0.f;
      wsum += w;
      unsigned short hb = bf16_rne(w);
      float hf = __uint_as_float((unsigned)hb << 16);
      a_hi[e] = (short)hb;
      a_lo[e] = (short)bf16_rne(w - hf);
    }
#pragma unroll
    for (int ff = 0; ff < 4; ff++) {
      short8v b_hi = *(const short8v*)(hTu + boff[ff] + qa);
      acc[ff] = __builtin_amdgcn_mfma_f32_16x16x32_bf16(a_hi, b_hi, acc[ff], 0, 0, 0);
      acc[ff] = __builtin_amdgcn_mfma_f32_16x16x32_bf16(a_lo, b_hi, acc[ff], 0, 0, 0);
    }
  }
  // denominator: reduce over kgrp lanes (same col)
  wsum += __shfl_xor(wsum, 16);
  wsum += __shfl_xor(wsum, 32);
  if (kgrp == 0) dnz[((size_t)head * QS + blockIdx.z) * N + p] = wsum;
  // accumulate numerator: D layout col=lane&15 (f), row=kgrp*4+r (p)
  float* __restrict__ hpb = hp + ((size_t)head * N + p0 + wid * 16) * 64;
#pragma unroll
  for (int ff = 0; ff < 4; ff++) {
#pragma unroll
    for (int r = 0; r < 4; r++) {
      unsafeAtomicAdd(&hpb[(kgrp * 4 + r) * 64 + ff * 16 + col], acc[ff][r]);
    }
  }
}

// ---------------- epilogue: sum denom slices, normalize, ELU, concat layout ----------------
__global__ void concat_elu_kernel(const float* __restrict__ hp, const float* __restrict__ dnz,
                                  float* __restrict__ xout) {
  int idx = blockIdx.x * 256 + threadIdx.x; // H*N*64
  int f = idx & 63;
  int n = (idx >> 6) & (N - 1);
  int head = idx >> 17;
  float dn = 0.f;
#pragma unroll
  for (int z = 0; z < QS; z++) dn += dnz[((size_t)head * QS + z) * N + n];
  float v = hp[idx] / dn;
  v = v > 0.f ? v : (__expf(v) - 1.f);
  xout[(size_t)n * (H * 64) + head * 64 + f] = v;
}

// ---------------- layer-2 projection (F_out=3) ----------------
__global__ void h3_kernel(const float* __restrict__ x, const float* __restrict__ W,
                          const float* __restrict__ a, float* __restrict__ h2,
                          float* __restrict__ s1, float* __restrict__ s2) {
  const int n = blockIdx.x;
  const int head = threadIdx.x >> 6, o = threadIdx.x & 63;
  __shared__ float xr[256];
  xr[threadIdx.x] = x[(size_t)n * 256 + threadIdx.x];
  __syncthreads();
  const float* __restrict__ Wh = W + (size_t)head * 256 * 3;
  float a3[3] = {0.f, 0.f, 0.f};
#pragma unroll
  for (int i = 0; i < 4; i++) {
    int k = o + 64 * i;
    float xv = xr[k];
    a3[0] = fmaf(xv, Wh[k * 3 + 0], a3[0]);
    a3[1] = fmaf(xv, Wh[k * 3 + 1], a3[1]);
    a3[2] = fmaf(xv, Wh[k * 3 + 2], a3[2]);
  }
#pragma unroll
  for (int f = 0; f < 3; f++)
    for (int s = 32; s; s >>= 1) a3[f] += __shfl_xor(a3[f], s);
  if (o == 0) {
    float p1 = 0.f, p2 = 0.f;
#pragma unroll
    for (int f = 0; f < 3; f++) {
      h2[((size_t)head * N + n) * 3 + f] = a3[f];
      p1 = fmaf(a3[f], a[head * 6 + f], p1);
      p2 = fmaf(a3[f], a[head * 6 + 3 + f], p2);
    }
    s1[head * N + n] = p1;
    s2[head * N + n] = p2;
  }
}

// ---------------- layer-2 aggregation, self-normalizing, fused head-mean + ELU -> emb ----------------
__global__ void agg2_kernel(const float* __restrict__ h2, const float* __restrict__ s1,
                            const float* __restrict__ s2, const float* __restrict__ mh,
                            const unsigned long long* __restrict__ mask,
                            float* __restrict__ emb) {
  const int p = blockIdx.x;
  const int head = threadIdx.x >> 6, lane = threadIdx.x & 63;
  const float s2p = s2[head * N + p];
  const float mhv = mh[head];
  const float* __restrict__ s1h = s1 + head * N;
  float a0 = 0.f, a1 = 0.f, a2 = 0.f, wsum = 0.f;
#pragma unroll 2
  for (int i = 0; i < 32; i++) {
    unsigned long long mwd = mask[(size_t)p * NW + i];
    int q = i * 64 + lane;
    if ((mwd >> lane) & 1ull) {
      float e = s1h[q] + s2p;
      e = fmaxf(e, ALPHA * e);
      float w = __expf(e - mhv);
      const float* __restrict__ hq = h2 + ((size_t)head * N + q) * 3;
      a0 = fmaf(w, hq[0], a0);
      a1 = fmaf(w, hq[1], a1);
      a2 = fmaf(w, hq[2], a2);
      wsum += w;
    }
  }
  for (int s = 32; s; s >>= 1) {
    a0 += __shfl_xor(a0, s); a1 += __shfl_xor(a1, s);
    a2 += __shfl_xor(a2, s); wsum += __shfl_xor(wsum, s);
  }
  __shared__ float red[4][4];
  if (lane == 0) { red[head][0] = a0; red[head][1] = a1; red[head][2] = a2; red[head][3] = wsum; }
  __syncthreads();
  if (threadIdx.x < 3) {
    int f = threadIdx.x;
    float v = 0.f;
#pragma unroll
    for (int hh = 0; hh < 4; hh++) v += red[hh][f] / red[hh][3];
    v *= 0.25f;
    v = v > 0.f ? v : (__expf(v) - 1.f);
    emb[p * 3 + f] = v;
  }
}

// ---------------- all-pairs edge classifier ----------------
__global__ void cls_kernel(const float* __restrict__ emb,
                           const float* __restrict__ W1, const float* __restrict__ b1,
                           const float* __restrict__ W2, const float* __restrict__ b2,
                           float* __restrict__ out) {
  int q = blockIdx.x * 256 + threadIdx.x;
  int p0 = blockIdx.y * 8;
  __shared__ float ep[8][3];
  __shared__ float w1s[96], b1s[32], w2s[32];
  __shared__ float b2s;
  int t = threadIdx.x;
  if (t < 96) w1s[t] = W1[t];
  else if (t < 128) b1s[t - 96] = b1[t - 96];
  else if (t < 160) w2s[t - 128] = W2[t - 128];
  else if (t == 160) b2s = b2[0];
  else if (t >= 192 && t < 216) ((float*)ep)[t - 192] = emb[p0 * 3 + t - 192];
  __syncthreads();
  float e0 = emb[q * 3 + 0], e1 = emb[q * 3 + 1], e2 = emb[q * 3 + 2];
  float d[8][3];
#pragma unroll
  for (int i = 0; i < 8; i++) {
    d[i][0] = fabsf(ep[i][0] - e0);
    d[i][1] = fabsf(ep[i][1] - e1);
    d[i][2] = fabsf(ep[i][2] - e2);
  }
  float acc[8] = {0, 0, 0, 0, 0, 0, 0, 0};
#pragma unroll
  for (int j = 0; j < 32; j++) {
    float c0 = w1s[j], c1 = w1s[32 + j], c2 = w1s[64 + j], bb = b1s[j], w2 = w2s[j];
#pragma unroll
    for (int i = 0; i < 8; i++) {
      float hv = fmaxf(bb + d[i][0] * c0 + d[i][1] * c1 + d[i][2] * c2, 0.f);
      acc[i] += hv * w2;
    }
  }
#pragma unroll
  for (int i = 0; i < 8; i++) {
    float x = acc[i] + b2s;
    out[(size_t)(p0 + i) * N + q] = 1.f / (1.f + __expf(-x));
  }
}

extern "C" void kernel_launch(void* const* d_in, const int* in_sizes, int n_in,
                              void* d_out, int out_size, void* d_ws, size_t ws_size,
                              hipStream_t stream) {
  const float* nf    = (const float*)d_in[0];
  const int*   adj   = (const int*)d_in[1];
  const float* encW1 = (const float*)d_in[2];
  const float* encb1 = (const float*)d_in[3];
  const float* encW2 = (const float*)d_in[4];
  const float* encb2 = (const float*)d_in[5];
  const float* gatW0 = (const float*)d_in[6];
  const float* gata0 = (const float*)d_in[7];
  const float* gatW1 = (const float*)d_in[8];
  const float* gata1 = (const float*)d_in[9];
  const float* gatW2 = (const float*)d_in[10];
  const float* gata2 = (const float*)d_in[11];
  const float* clsW1 = (const float*)d_in[12];
  const float* clsb1 = (const float*)d_in[13];
  const float* clsW2 = (const float*)d_in[14];
  const float* clsb2 = (const float*)d_in[15];

  float* ws = (float*)d_ws;
  __hip_bfloat16* hT = (__hip_bfloat16*)ws;      // bf16 [H][64][N] = 262144 float-equiv
  float* s1  = ws + 262144;                      // H*N
  float* s2  = s1 + 8192;
  float* mh  = s2 + 8192;                        // 64 (4 used)
  float* dnz = mh + 64;                          // H*QS*N = 65536
  float* hp  = dnz + 65536;                      // H*N*64 = 524288
  float* xA  = hp + 524288;                      // N*256
  float* xB  = xA + 524288;                      // N*256
  float* h2  = xB + 524288;                      // H*N*3
  unsigned long long* mask = (unsigned long long*)(h2 + 24576); // N*NW words (512 KB)

  float* emb = (float*)d_out;                    // 2048*3
  float* eprob = emb + N * 3;                    // 2048*2048

  pack_adj_kernel<<<dim3(N * NW / 4), dim3(256), 0, stream>>>(adj, mask);

  // ---- GAT layer 0 (fused encoder + projection) ----
  enc_h0_kernel<<<dim3(N / 4), dim3(256), 0, stream>>>(nf, encW1, encb1, encW2, encb2,
                                                       gatW0, gata0, hT, s1, s2);
  maxred_kernel<<<dim3(H), dim3(256), 0, stream>>>(s1, s2, mh);
  hipMemsetAsync(hp, 0, (size_t)H * N * 64 * sizeof(float), stream);
  agg_mfma_kernel<<<dim3(N / 64, H, QS), dim3(256), 0, stream>>>(hT, s1, s2, mh, mask, hp, dnz);
  concat_elu_kernel<<<dim3(H * N * 64 / 256), dim3(256), 0, stream>>>(hp, dnz, xA);

  // ---- GAT layer 1 (in_f=256) ----
  h_all_kernel<<<dim3(N / 4), dim3(256), 0, stream>>>(xA, gatW1, gata1, hT, s1, s2);
  maxred_kernel<<<dim3(H), dim3(256), 0, stream>>>(s1, s2, mh);
  hipMemsetAsync(hp, 0, (size_t)H * N * 64 * sizeof(float), stream);
  agg_mfma_kernel<<<dim3(N / 64, H, QS), dim3(256), 0, stream>>>(hT, s1, s2, mh, mask, hp, dnz);
  concat_elu_kernel<<<dim3(H * N * 64 / 256), dim3(256), 0, stream>>>(hp, dnz, xB);

  // ---- GAT layer 2 (F_out=3, mean over heads) ----
  h3_kernel<<<dim3(N), dim3(256), 0, stream>>>(xB, gatW2, gata2, h2, s1, s2);
  maxred_kernel<<<dim3(H), dim3(256), 0, stream>>>(s1, s2, mh);
  agg2_kernel<<<dim3(N), dim3(256), 0, stream>>>(h2, s1, s2, mh, mask, emb);

  // ---- classifier ----
  cls_kernel<<<dim3(8, N / 8), dim3(256), 0, stream>>>(emb, clsW1, clsb1, clsW2, clsb2, eprob);
}